// Round 3
// baseline (530.605 us; speedup 1.0000x reference)
//
#include <hip/hip_runtime.h>
#include <stdint.h>

#define NROWS 65536
#define DCOL  480      // 128 + 3*64 + 5*32
#define RT    16       // rows per block

#define INV_S0 0.08838834764831845f   // 1/sqrt(128)
#define INV_S1 0.125f                  // 1/8
#define INV_S2 0.17677669529663687f    // 1/sqrt(32)
#define INV_T0 0.044194173824159216f   // 1/sqrt(512)
#define INV_T1 0.0625f                 // 1/16
#define INV_T2 0.08838834764831845f    // 1/sqrt(128)

// d_ws element offsets (uint16_t units), fragment-linear transposed layouts Wt[n][k]
#define OFF_W0T 0         // [896][128]  (x INV_S0 folded)
#define OFF_W1T 114688    // [256][64]   (x INV_S1)
#define OFF_W2T 131072    // [128][32]   (x INV_S2)
#define OFF_V0T 135168    // [128][512]  (x INV_T0)
#define OFF_V1T 200704    // [64][256]   (x INV_T1)
#define OFF_V2T 217088    // [32][128]   (x INV_T2)
#define TOT_W   221184

typedef __attribute__((ext_vector_type(8))) short  short8;
typedef __attribute__((ext_vector_type(4))) float  floatx4;

__device__ __forceinline__ uint16_t f2bf(float x){
  uint32_t u = __builtin_bit_cast(uint32_t, x);
  return (uint16_t)((u + 0x8000u) >> 16);
}
__device__ __forceinline__ float bf2f(uint16_t h){
  return __builtin_bit_cast(float, (uint32_t)h << 16);
}

#define MFMA16(a,b,c) __builtin_amdgcn_mfma_f32_16x16x32_bf16((a),(b),(c),0,0,0)

// ---------------- weight conversion pre-pass: fp32 row-major -> bf16 Wt[n][k], scale folded
__global__ __launch_bounds__(256)
void convert_weights(const float* __restrict__ W0, const float* __restrict__ W1,
                     const float* __restrict__ W2, const float* __restrict__ V0,
                     const float* __restrict__ V1, const float* __restrict__ V2,
                     uint16_t* __restrict__ wt)
{
  const int tid = blockIdx.x*256 + threadIdx.x;
  if (tid >= TOT_W) return;
  if (tid < OFF_W1T){
    const int i = tid;            const int n = i>>7, k = i&127;
    wt[tid] = f2bf(W0[(size_t)k*896 + n] * INV_S0);
  } else if (tid < OFF_W2T){
    const int i = tid - OFF_W1T;  const int n = i>>6, k = i&63;
    wt[tid] = f2bf(W1[(size_t)k*256 + n] * INV_S1);
  } else if (tid < OFF_V0T){
    const int i = tid - OFF_W2T;  const int n = i>>5, k = i&31;
    wt[tid] = f2bf(W2[(size_t)k*128 + n] * INV_S2);
  } else if (tid < OFF_V1T){
    const int i = tid - OFF_V0T;  const int n = i>>9, k = i&511;
    wt[tid] = f2bf(V0[(size_t)k*128 + n] * INV_T0);
  } else if (tid < OFF_V2T){
    const int i = tid - OFF_V1T;  const int n = i>>8, k = i&255;
    wt[tid] = f2bf(V1[(size_t)k*64 + n] * INV_T1);
  } else {
    const int i = tid - OFF_V2T;  const int n = i>>7, k = i&127;
    wt[tid] = f2bf(V2[(size_t)k*32 + n] * INV_T2);
  }
}

// ---------------- fused main kernel: 16 rows / 8 waves (512 thr) / 7-barrier overlapped
// Same window plan as before; per-wave work halved for 2x occupancy (6 waves/SIMD).
//   P1 | P2(h0->s,g) | W1: o0 + h2m0->z2b0 | W2: h1(m0,m1)->z1b0/b1 + h2m1->z2b1 + o2m0(z2b0)
//   W3: o1(m0,m1) + h2m2->z2b0 + o2m1(z2b1) | W4: h1m2->z1b0 + h2m3->z2b1 + o2m2(z2b0)
//   W5: o1m2(z1b0) + h2m4->z2b0 + o2m3(z2b1) | W6: o2m4(z2b0)
// Per-wave tile map (8 waves): o0/h2: tile=wave; h1: tiles wave,wave+8;
//   o1: m=wave>>2 (W3) tile=wave&3, m2 (W5) waves 0-3; o2 rotates wave pairs
//   {0,1}/{2,3}/{4,5}/{6,7}/{0,1} over m=0..4.
// U-region packing (bytes): y0[0,4352) s[4352,20992) | z2b1[0,4352) z1b0[4352,12800)
//   z1b1[12800,21248) z2b0[21248,25600)  -- verified disjoint per window.
__global__ __launch_bounds__(512, 6)
void ffn_mfma(const float* __restrict__ x,  const float* __restrict__ nw0,
              const float* __restrict__ nb0,const float* __restrict__ nw1,
              const float* __restrict__ nw2,const float* __restrict__ b0,
              const float* __restrict__ c0, const float* __restrict__ alpha,
              const uint16_t* __restrict__ wt, float* __restrict__ out)
{
  __shared__ __align__(16) uint16_t y1bf[3][16][72];   // 6912 B
  __shared__ __align__(16) uint16_t y2bf[5][16][40];   // 6400 B
  __shared__ __align__(16) uint16_t gbf[16][392];      // 12544 B
  __shared__ __align__(16) uint16_t Ubuf[12800];       // 25600 B union region

  uint16_t (*y0bf)[136] = (uint16_t (*)[136])(Ubuf);          // [16][136]
  uint16_t (*sbf )[520] = (uint16_t (*)[520])(Ubuf + 2176);   // [16][520]
  uint16_t (*z1b0)[264] = (uint16_t (*)[264])(Ubuf + 2176);   // [16][264]
  uint16_t (*z1b1)[264] = (uint16_t (*)[264])(Ubuf + 6400);   // [16][264]
  uint16_t (*z2b0)[136] = (uint16_t (*)[136])(Ubuf + 10624);  // [16][136]
  uint16_t (*z2b1)[136] = (uint16_t (*)[136])(Ubuf);          // [16][136]

  const int t      = threadIdx.x;
  const int wave   = t >> 6, lane = t & 63;
  const int lane16 = lane & 15, quad = lane >> 4;
  const int row0   = blockIdx.x * RT;
  const float ta   = tanhf(alpha[0]);
  const floatx4 fz = {0.f,0.f,0.f,0.f};

  // ---------- P1: norms -> y0/y1/y2 (2 rows per wave) ----------
  {
    float xv[2][8];
    const int rbase = wave*2;
    #pragma unroll
    for (int rr=0; rr<2; ++rr){
      const float* xr = x + (size_t)(row0 + rbase + rr)*DCOL;
      #pragma unroll
      for (int i=0;i<8;++i){ const int e = lane + i*64; xv[rr][i] = (e < DCOL) ? xr[e] : 0.f; }
    }
    // per-lane constants (identical across rows -> load once)
    float wA[8], wB[8]; int uu[8], mmv[8];
    #pragma unroll
    for (int i=0;i<8;++i){
      const int e = lane + i*64;
      if (e < 128){ uu[i]=e; mmv[i]=0; wA[i]=nw0[e]; wB[i]=nb0[e]; }
      else if (e < 320){ const int d=e-128; const int u=d/3; uu[i]=u; mmv[i]=d-3*u; wA[i]=nw1[u]; wB[i]=0.f; }
      else if (e < DCOL){ const int d=e-320; const int u=d/5; uu[i]=u; mmv[i]=d-5*u; wA[i]=nw2[u]; wB[i]=0.f; }
      else { uu[i]=0; mmv[i]=0; wA[i]=0.f; wB[i]=0.f; }
    }
    #pragma unroll
    for (int rr=0; rr<2; ++rr){
      const int r = rbase + rr;
      float s0  = xv[rr][0] + xv[rr][1];
      float s0q = xv[rr][0]*xv[rr][0] + xv[rr][1]*xv[rr][1];
      float q1  = xv[rr][2]*xv[rr][2] + xv[rr][3]*xv[rr][3] + xv[rr][4]*xv[rr][4];
      float q2  = xv[rr][5]*xv[rr][5] + xv[rr][6]*xv[rr][6] + xv[rr][7]*xv[rr][7];
      #pragma unroll
      for (int off=32; off>0; off>>=1){
        s0  += __shfl_xor(s0,  off);
        s0q += __shfl_xor(s0q, off);
        q1  += __shfl_xor(q1,  off);
        q2  += __shfl_xor(q2,  off);
      }
      const float mu   = s0 * (1.f/128.f);
      const float var  = s0q * (1.f/128.f) - mu*mu;
      const float rstd = rsqrtf(var + 1e-8f);
      const float inv  = rsqrtf(0.5f*(q1*(1.f/192.f) + q2*(1.f/160.f)) + 1e-8f);
      #pragma unroll
      for (int i=0;i<8;++i){
        const int e = lane + i*64;
        if (e < 128)       y0bf[r][e] = f2bf((xv[rr][i]-mu)*rstd*wA[i] + wB[i]);
        else if (e < 320)  y1bf[mmv[i]][r][uu[i]] = f2bf(xv[rr][i]*inv*wA[i]);
        else if (e < DCOL) y2bf[mmv[i]][r][uu[i]] = f2bf(xv[rr][i]*inv*wA[i]);
      }
    }
  }
  __syncthreads();

  // ---------- P2: h0 = y0@W0 + b0 -> silu/sigmoid -> sbf/gbf (7 tiles/wave, ping-pong) ----------
  {
    short8 a0[4];
    #pragma unroll
    for (int kk=0; kk<4; ++kk)
      a0[kk] = *(const short8*)&y0bf[lane16][kk*32 + quad*8];
    const uint16_t* W0t = wt + OFF_W0T;

    auto ldW0 = [&](int tile, short8* dst){
      #pragma unroll
      for (int kk=0;kk<4;++kk)
        dst[kk] = *(const short8*)(W0t + (size_t)(tile*16+lane16)*128 + kk*32 + quad*8);
    };
    auto h0_tile = [&](int tile, const short8* bfr){
      floatx4 acc = fz;
      #pragma unroll
      for (int kk=0;kk<4;++kk) acc = MFMA16(a0[kk], bfr[kk], acc);
      const int col  = tile*16 + lane16;
      const float bias = b0[col];
      #pragma unroll
      for (int r2=0; r2<4; ++r2){
        const int row = quad*4 + r2;
        const float h  = acc[r2] + bias;
        const float sg = 1.f/(1.f + __expf(-h));
        if (col < 512) sbf[row][col]       = f2bf(h*sg);   // silu
        else           gbf[row][col - 512] = f2bf(sg);     // gate
      }
    };

    short8 buf[2][4];
    ldW0(wave, buf[0]);
    #pragma unroll
    for (int it=0; it<7; ++it){          // tiles wave, wave+8, ..., wave+48
      const int cur = it & 1;
      if (it < 6) ldW0(wave + (it+1)*8, buf[cur^1]);
      h0_tile(wave + it*8, buf[cur]);
    }
  }
  __syncthreads();

  // ---------- W1: o0 = s@V0 + c0 (tile=wave) ∥ h2(m=0)->z2b0 (tile=wave) ----------
  {
    const uint16_t* W2t = wt + OFF_W2T;
    const uint16_t* V0t = wt + OFF_V0T;
    const int n0 = wave*16;
    const int col = n0 + lane16;
    // early: h2 m0 operands + o0 residual x loads (latency hides under o0 MFMA loop)
    const short8 a2 = *(const short8*)&y2bf[0][lane16][quad*8];
    const short8 hb = *(const short8*)(W2t + (size_t)col*32 + quad*8);
    float xra[4];
    #pragma unroll
    for (int r2=0;r2<4;++r2)
      xra[r2] = x[(size_t)(row0+quad*4+r2)*DCOL + col];
    floatx4 acc0 = fz;
    #pragma unroll 4
    for (int kk=0; kk<16; ++kk){
      const short8 a  = *(const short8*)&sbf[lane16][kk*32 + quad*8];
      const short8 ba = *(const short8*)(V0t + (size_t)col*512 + kk*32 + quad*8);
      acc0 = MFMA16(a, ba, acc0);
    }
    // h2 m0 finish -> z2b0
    {
      floatx4 ha = MFMA16(a2, hb, fz);
      #pragma unroll
      for (int r2=0;r2<4;++r2){
        const int row = quad*4+r2;
        z2b0[row][col] = f2bf(ha[r2]*bf2f(gbf[row][256+col]));
      }
    }
    // o0 stores
    const float cca = c0[col];
    #pragma unroll
    for (int r2=0;r2<4;++r2){
      const int row = quad*4+r2;
      out[(size_t)(row0+row)*DCOL + col] = xra[r2] + ta*(acc0[r2]+cca);
    }
  }
  __syncthreads();

  // ---------- W2: h1(m0,m1)->z1b0/b1 (tiles wave,wave+8) ∥ h2(m1)->z2b1 ∥ o2m0 (waves 0,1) ----------
  {
    const uint16_t* W1t = wt + OFF_W1T;
    const uint16_t* W2t = wt + OFF_W2T;
    const uint16_t* V2t = wt + OFF_V2T;
    const int hcol = wave*16 + lane16;
    // h2 m1 early loads
    const short8 a2 = *(const short8*)&y2bf[1][lane16][quad*8];
    const short8 hb = *(const short8*)(W2t + (size_t)hcol*32 + quad*8);
    // o2 m0 early loads (waves 0,1)
    short8 ob[4]; float xro[4];
    if (wave < 2){
      const int n0 = wave*16;
      #pragma unroll
      for (int kk=0;kk<4;++kk)
        ob[kk] = *(const short8*)(V2t + (size_t)(n0+lane16)*128 + kk*32 + quad*8);
      #pragma unroll
      for (int r2=0;r2<4;++r2)
        xro[r2] = x[(size_t)(row0+quad*4+r2)*DCOL + 320 + (n0+lane16)*5 + 0];
    }
    // h1 m0,m1 (B fragments shared between both m)
    short8 a10[2], a11[2];
    a10[0] = *(const short8*)&y1bf[0][lane16][quad*8];
    a10[1] = *(const short8*)&y1bf[0][lane16][32 + quad*8];
    a11[0] = *(const short8*)&y1bf[1][lane16][quad*8];
    a11[1] = *(const short8*)&y1bf[1][lane16][32 + quad*8];
    #pragma unroll
    for (int tt=0; tt<2; ++tt){
      const int n0 = (wave + tt*8)*16;
      const short8 b0f = *(const short8*)(W1t + (size_t)(n0+lane16)*64 + quad*8);
      const short8 b1f = *(const short8*)(W1t + (size_t)(n0+lane16)*64 + 32 + quad*8);
      floatx4 am0 = fz, am1 = fz;
      am0 = MFMA16(a10[0], b0f, am0); am0 = MFMA16(a10[1], b1f, am0);
      am1 = MFMA16(a11[0], b0f, am1); am1 = MFMA16(a11[1], b1f, am1);
      const int col = n0 + lane16;
      #pragma unroll
      for (int r2=0;r2<4;++r2){
        const int row = quad*4 + r2;
        const float g = bf2f(gbf[row][col]);
        z1b0[row][col] = f2bf(am0[r2]*g);
        z1b1[row][col] = f2bf(am1[r2]*g);
      }
    }
    // h2 m1 finish -> z2b1
    {
      floatx4 ha = MFMA16(a2, hb, fz);
      #pragma unroll
      for (int r2=0;r2<4;++r2){
        const int row = quad*4+r2;
        z2b1[row][hcol] = f2bf(ha[r2]*bf2f(gbf[row][256+hcol]));
      }
    }
    // o2 m0 (waves 0,1) reads z2b0
    if (wave < 2){
      const int n0 = wave*16;
      floatx4 acc = fz;
      #pragma unroll
      for (int kk=0;kk<4;++kk){
        const short8 a = *(const short8*)&z2b0[lane16][kk*32 + quad*8];
        acc = MFMA16(a, ob[kk], acc);
      }
      const int col = n0 + lane16;
      #pragma unroll
      for (int r2=0;r2<4;++r2){
        const int row = quad*4+r2;
        const size_t idx = (size_t)(row0+row)*DCOL + 320 + col*5 + 0;
        out[idx] = xro[r2] + ta*acc[r2];
      }
    }
  }
  __syncthreads();

  // ---------- W3: o1(m=wave>>2, tile=wave&3) ∥ h2(m2)->z2b0 ∥ o2m1 (waves 2,3) ----------
  {
    const uint16_t* V1t = wt + OFF_V1T;
    const uint16_t* W2t = wt + OFF_W2T;
    const uint16_t* V2t = wt + OFF_V2T;
    const int hcol = wave*16 + lane16;
    // h2 m2 early loads
    const short8 a2 = *(const short8*)&y2bf[2][lane16][quad*8];
    const short8 hb = *(const short8*)(W2t + (size_t)hcol*32 + quad*8);
    // o2 m1 early loads (waves 2,3)
    short8 ob[4]; float xro[4];
    if (wave == 2 || wave == 3){
      const int n0 = (wave-2)*16;
      #pragma unroll
      for (int kk=0;kk<4;++kk)
        ob[kk] = *(const short8*)(V2t + (size_t)(n0+lane16)*128 + kk*32 + quad*8);
      #pragma unroll
      for (int r2=0;r2<4;++r2)
        xro[r2] = x[(size_t)(row0+quad*4+r2)*DCOL + 320 + (n0+lane16)*5 + 1];
    }
    // o1: m = wave>>2 in {0,1}, tile = wave&3
    const int mo = wave >> 2;
    const int n0 = (wave & 3)*16;
    const int col = n0 + lane16;
    float xr0[4];
    #pragma unroll
    for (int r2=0;r2<4;++r2)
      xr0[r2] = x[(size_t)(row0+quad*4+r2)*DCOL + 128 + col*3 + mo];
    const uint16_t (*zb)[264] = mo ? z1b1 : z1b0;
    floatx4 am0 = fz;
    #pragma unroll 4
    for (int kk=0; kk<8; ++kk){
      const short8 af = *(const short8*)&zb[lane16][kk*32 + quad*8];
      const short8 b  = *(const short8*)(V1t + (size_t)col*256 + kk*32 + quad*8);
      am0 = MFMA16(af, b, am0);
    }
    #pragma unroll
    for (int r2=0;r2<4;++r2){
      const int row = quad*4+r2;
      out[(size_t)(row0+row)*DCOL + 128 + col*3 + mo] = xr0[r2] + ta*am0[r2];
    }
    // h2 m2 finish -> z2b0
    {
      floatx4 ha = MFMA16(a2, hb, fz);
      #pragma unroll
      for (int r2=0;r2<4;++r2){
        const int row = quad*4+r2;
        z2b0[row][hcol] = f2bf(ha[r2]*bf2f(gbf[row][256+hcol]));
      }
    }
    // o2 m1 (waves 2,3) reads z2b1
    if (wave == 2 || wave == 3){
      const int n02 = (wave-2)*16;
      floatx4 acc = fz;
      #pragma unroll
      for (int kk=0;kk<4;++kk){
        const short8 a = *(const short8*)&z2b1[lane16][kk*32 + quad*8];
        acc = MFMA16(a, ob[kk], acc);
      }
      const int c2 = n02 + lane16;
      #pragma unroll
      for (int r2=0;r2<4;++r2){
        const int row = quad*4+r2;
        const size_t idx = (size_t)(row0+row)*DCOL + 320 + c2*5 + 1;
        out[idx] = xro[r2] + ta*acc[r2];
      }
    }
  }
  __syncthreads();

  // ---------- W4: h1(m2)->z1b0 (tiles wave,wave+8) ∥ h2(m3)->z2b1 ∥ o2m2 (waves 4,5) ----------
  {
    const uint16_t* W1t = wt + OFF_W1T;
    const uint16_t* W2t = wt + OFF_W2T;
    const uint16_t* V2t = wt + OFF_V2T;
    const int hcol = wave*16 + lane16;
    const short8 a2 = *(const short8*)&y2bf[3][lane16][quad*8];
    const short8 hb = *(const short8*)(W2t + (size_t)hcol*32 + quad*8);
    short8 ob[4]; float xro[4];
    if (wave == 4 || wave == 5){
      const int n0 = (wave-4)*16;
      #pragma unroll
      for (int kk=0;kk<4;++kk)
        ob[kk] = *(const short8*)(V2t + (size_t)(n0+lane16)*128 + kk*32 + quad*8);
      #pragma unroll
      for (int r2=0;r2<4;++r2)
        xro[r2] = x[(size_t)(row0+quad*4+r2)*DCOL + 320 + (n0+lane16)*5 + 2];
    }
    short8 a12[2];
    a12[0] = *(const short8*)&y1bf[2][lane16][quad*8];
    a12[1] = *(const short8*)&y1bf[2][lane16][32 + quad*8];
    #pragma unroll
    for (int tt=0; tt<2; ++tt){
      const int n0 = (wave + tt*8)*16;
      const short8 b0f = *(const short8*)(W1t + (size_t)(n0+lane16)*64 + quad*8);
      const short8 b1f = *(const short8*)(W1t + (size_t)(n0+lane16)*64 + 32 + quad*8);
      floatx4 am = fz;
      am = MFMA16(a12[0], b0f, am); am = MFMA16(a12[1], b1f, am);
      const int col = n0 + lane16;
      #pragma unroll
      for (int r2=0;r2<4;++r2){
        const int row = quad*4 + r2;
        z1b0[row][col] = f2bf(am[r2]*bf2f(gbf[row][col]));
      }
    }
    // h2 m3 -> z2b1
    {
      floatx4 ha = MFMA16(a2, hb, fz);
      #pragma unroll
      for (int r2=0;r2<4;++r2){
        const int row = quad*4+r2;
        z2b1[row][hcol] = f2bf(ha[r2]*bf2f(gbf[row][256+hcol]));
      }
    }
    // o2 m2 (waves 4,5) reads z2b0
    if (wave == 4 || wave == 5){
      const int n0 = (wave-4)*16;
      floatx4 acc = fz;
      #pragma unroll
      for (int kk=0;kk<4;++kk){
        const short8 a = *(const short8*)&z2b0[lane16][kk*32 + quad*8];
        acc = MFMA16(a, ob[kk], acc);
      }
      const int col = n0 + lane16;
      #pragma unroll
      for (int r2=0;r2<4;++r2){
        const int row = quad*4+r2;
        const size_t idx = (size_t)(row0+row)*DCOL + 320 + col*5 + 2;
        out[idx] = xro[r2] + ta*acc[r2];
      }
    }
  }
  __syncthreads();

  // ---------- W5: o1(m2, waves 0-3) ∥ h2(m4)->z2b0 ∥ o2m3 (waves 6,7) ----------
  {
    const uint16_t* V1t = wt + OFF_V1T;
    const uint16_t* W2t = wt + OFF_W2T;
    const uint16_t* V2t = wt + OFF_V2T;
    const int hcol = wave*16 + lane16;
    const short8 a2 = *(const short8*)&y2bf[4][lane16][quad*8];
    const short8 hb = *(const short8*)(W2t + (size_t)hcol*32 + quad*8);
    short8 ob[4]; float xro[4];
    if (wave >= 6){
      const int n0 = (wave-6)*16;
      #pragma unroll
      for (int kk=0;kk<4;++kk)
        ob[kk] = *(const short8*)(V2t + (size_t)(n0+lane16)*128 + kk*32 + quad*8);
      #pragma unroll
      for (int r2=0;r2<4;++r2)
        xro[r2] = x[(size_t)(row0+quad*4+r2)*DCOL + 320 + (n0+lane16)*5 + 3];
    }
    // o1 m2 (waves 0-3, tile = wave)
    if (wave < 4){
      const int n0 = wave*16;
      const int col = n0 + lane16;
      float xr2[4];
      #pragma unroll
      for (int r2=0;r2<4;++r2)
        xr2[r2] = x[(size_t)(row0+quad*4+r2)*DCOL + 128 + col*3 + 2];
      floatx4 am = fz;
      #pragma unroll 4
      for (int kk=0; kk<8; ++kk){
        const short8 a = *(const short8*)&z1b0[lane16][kk*32 + quad*8];
        const short8 b = *(const short8*)(V1t + (size_t)col*256 + kk*32 + quad*8);
        am = MFMA16(a, b, am);
      }
      #pragma unroll
      for (int r2=0;r2<4;++r2){
        const int row = quad*4+r2;
        out[(size_t)(row0+row)*DCOL + 128 + col*3 + 2] = xr2[r2] + ta*am[r2];
      }
    }
    // h2 m4 -> z2b0
    {
      floatx4 ha = MFMA16(a2, hb, fz);
      #pragma unroll
      for (int r2=0;r2<4;++r2){
        const int row = quad*4+r2;
        z2b0[row][hcol] = f2bf(ha[r2]*bf2f(gbf[row][256+hcol]));
      }
    }
    // o2 m3 (waves 6,7) reads z2b1
    if (wave >= 6){
      const int n02 = (wave-6)*16;
      floatx4 acc = fz;
      #pragma unroll
      for (int kk=0;kk<4;++kk){
        const short8 a = *(const short8*)&z2b1[lane16][kk*32 + quad*8];
        acc = MFMA16(a, ob[kk], acc);
      }
      const int c2 = n02 + lane16;
      #pragma unroll
      for (int r2=0;r2<4;++r2){
        const int row = quad*4+r2;
        const size_t idx = (size_t)(row0+row)*DCOL + 320 + c2*5 + 3;
        out[idx] = xro[r2] + ta*acc[r2];
      }
    }
  }
  __syncthreads();

  // ---------- W6: o2(m4) (waves 0,1) reads z2b0 ----------
  if (wave < 2){
    const uint16_t* V2t = wt + OFF_V2T;
    const int n0 = wave*16;
    short8 ob[4]; float xro[4];
    #pragma unroll
    for (int kk=0;kk<4;++kk)
      ob[kk] = *(const short8*)(V2t + (size_t)(n0+lane16)*128 + kk*32 + quad*8);
    #pragma unroll
    for (int r2=0;r2<4;++r2)
      xro[r2] = x[(size_t)(row0+quad*4+r2)*DCOL + 320 + (n0+lane16)*5 + 4];
    floatx4 acc = fz;
    #pragma unroll
    for (int kk=0;kk<4;++kk){
      const short8 a = *(const short8*)&z2b0[lane16][kk*32 + quad*8];
      acc = MFMA16(a, ob[kk], acc);
    }
    const int col = n0 + lane16;
    #pragma unroll
    for (int r2=0;r2<4;++r2){
      const int row = quad*4+r2;
      const size_t idx = (size_t)(row0+row)*DCOL + 320 + col*5 + 4;
      out[idx] = xro[r2] + ta*acc[r2];
    }
  }
}

extern "C" void kernel_launch(void* const* d_in, const int* in_sizes, int n_in,
                              void* d_out, int out_size, void* d_ws, size_t ws_size,
                              hipStream_t stream) {
  const float* x   = (const float*)d_in[0];
  const float* nw0 = (const float*)d_in[1];
  const float* nb0 = (const float*)d_in[2];
  const float* nw1 = (const float*)d_in[3];
  const float* nw2 = (const float*)d_in[4];
  const float* W0  = (const float*)d_in[5];
  const float* b0  = (const float*)d_in[6];
  const float* W1  = (const float*)d_in[7];
  const float* W2  = (const float*)d_in[8];
  const float* V0  = (const float*)d_in[9];
  const float* c0  = (const float*)d_in[10];
  const float* V1  = (const float*)d_in[11];
  const float* V2  = (const float*)d_in[12];
  const float* al  = (const float*)d_in[13];
  uint16_t* wt = (uint16_t*)d_ws;   // needs 442368 B

  convert_weights<<<dim3((TOT_W + 255)/256), dim3(256), 0, stream>>>(
      W0, W1, W2, V0, V1, V2, wt);
  ffn_mfma<<<dim3(NROWS/RT), dim3(512), 0, stream>>>(
      x, nw0, nb0, nw1, nw2, b0, c0, al, wt, (float*)d_out);
}

// Round 4
// 429.875 us; speedup vs baseline: 1.2343x; 1.2343x over previous
//
#include <hip/hip_runtime.h>
#include <stdint.h>

#define NROWS 65536
#define DCOL  480      // 128 + 3*64 + 5*32
#define RT    16       // rows per block

#define INV_S0 0.08838834764831845f   // 1/sqrt(128)
#define INV_S1 0.125f                  // 1/8
#define INV_S2 0.17677669529663687f    // 1/sqrt(32)
#define INV_T0 0.044194173824159216f   // 1/sqrt(512)
#define INV_T1 0.0625f                 // 1/16
#define INV_T2 0.08838834764831845f    // 1/sqrt(128)

// d_ws element offsets (uint16_t units), fragment-linear transposed layouts Wt[n][k]
#define OFF_W0T 0         // [896][128]  (x INV_S0 folded)
#define OFF_W1T 114688    // [256][64]   (x INV_S1)
#define OFF_W2T 131072    // [128][32]   (x INV_S2)
#define OFF_V0T 135168    // [128][512]  (x INV_T0)
#define OFF_V1T 200704    // [64][256]   (x INV_T1)
#define OFF_V2T 217088    // [32][128]   (x INV_T2)
#define TOT_W   221184

typedef __attribute__((ext_vector_type(8))) short  short8;
typedef __attribute__((ext_vector_type(4))) float  floatx4;

__device__ __forceinline__ uint16_t f2bf(float x){
  uint32_t u = __builtin_bit_cast(uint32_t, x);
  return (uint16_t)((u + 0x8000u) >> 16);
}
__device__ __forceinline__ float bf2f(uint16_t h){
  return __builtin_bit_cast(float, (uint32_t)h << 16);
}

#define MFMA16(a,b,c) __builtin_amdgcn_mfma_f32_16x16x32_bf16((a),(b),(c),0,0,0)

// ---------------- weight conversion pre-pass: fp32 row-major -> bf16 Wt[n][k], scale folded
__global__ __launch_bounds__(256)
void convert_weights(const float* __restrict__ W0, const float* __restrict__ W1,
                     const float* __restrict__ W2, const float* __restrict__ V0,
                     const float* __restrict__ V1, const float* __restrict__ V2,
                     uint16_t* __restrict__ wt)
{
  const int tid = blockIdx.x*256 + threadIdx.x;
  if (tid >= TOT_W) return;
  if (tid < OFF_W1T){
    const int i = tid;            const int n = i>>7, k = i&127;
    wt[tid] = f2bf(W0[(size_t)k*896 + n] * INV_S0);
  } else if (tid < OFF_W2T){
    const int i = tid - OFF_W1T;  const int n = i>>6, k = i&63;
    wt[tid] = f2bf(W1[(size_t)k*256 + n] * INV_S1);
  } else if (tid < OFF_V0T){
    const int i = tid - OFF_W2T;  const int n = i>>5, k = i&31;
    wt[tid] = f2bf(W2[(size_t)k*128 + n] * INV_S2);
  } else if (tid < OFF_V1T){
    const int i = tid - OFF_V0T;  const int n = i>>9, k = i&511;
    wt[tid] = f2bf(V0[(size_t)k*128 + n] * INV_T0);
  } else if (tid < OFF_V2T){
    const int i = tid - OFF_V1T;  const int n = i>>8, k = i&255;
    wt[tid] = f2bf(V1[(size_t)k*64 + n] * INV_T1);
  } else {
    const int i = tid - OFF_V2T;  const int n = i>>7, k = i&127;
    wt[tid] = f2bf(V2[(size_t)k*32 + n] * INV_T2);
  }
}

// ---------------- fused main kernel: 16 rows / 8 waves / 4 barriers, line-dense writes
// Schedule: P1(norms) | P2(h0 -> s,g) | W1(o0 ∥ h2 all-m -> z2x5) |
//           W2(h1 all-m -> z1x3 ∥ o2 all-m reads z2) | W3(o1 all-m reads z1)
// All m-writes to any 64B out line land in ONE window -> L2 merges -> no HBM RMW.
// LDS pool 68608 B (lifetime-overlapped):
//   gbf [0,12544)  y1 [12544,19456)  z2 [19456,41216)  z1 [41216,66560)
//   y2 [41216,47616) sbf [47616,64256) y0 [64256,68608)  (y2/sbf/y0 dead before z1 writes)
// 2 blocks/CU (137 KB of 160 KB LDS) x 8 waves = 16 waves/CU.
__global__ __launch_bounds__(512, 4)
void ffn_mfma(const float* __restrict__ x,  const float* __restrict__ nw0,
              const float* __restrict__ nb0,const float* __restrict__ nw1,
              const float* __restrict__ nw2,const float* __restrict__ b0,
              const float* __restrict__ c0, const float* __restrict__ alpha,
              const uint16_t* __restrict__ wt, float* __restrict__ out)
{
  __shared__ __align__(16) uint16_t pool[34304];   // 68608 B

  uint16_t (*gbf )[392]      = (uint16_t (*)[392])     (pool);           // [16][392]
  uint16_t (*y1bf)[16][72]   = (uint16_t (*)[16][72])  (pool + 6272);    // [3][16][72]
  uint16_t (*z2bf)[16][136]  = (uint16_t (*)[16][136]) (pool + 9728);    // [5][16][136]
  uint16_t (*z1bf)[16][264]  = (uint16_t (*)[16][264]) (pool + 20608);   // [3][16][264]
  uint16_t (*y2bf)[16][40]   = (uint16_t (*)[16][40])  (pool + 20608);   // [5][16][40]
  uint16_t (*sbf )[520]      = (uint16_t (*)[520])     (pool + 23808);   // [16][520]
  uint16_t (*y0bf)[136]      = (uint16_t (*)[136])     (pool + 32128);   // [16][136]

  const int t      = threadIdx.x;
  const int wave   = t >> 6, lane = t & 63;
  const int lane16 = lane & 15, quad = lane >> 4;
  const int row0   = blockIdx.x * RT;
  const float ta   = tanhf(alpha[0]);
  const floatx4 fz = {0.f,0.f,0.f,0.f};

  // ---------- P1: norms -> y0/y1/y2 (2 rows per wave) ----------
  {
    float xv[2][8];
    const int rbase = wave*2;
    #pragma unroll
    for (int rr=0; rr<2; ++rr){
      const float* xr = x + (size_t)(row0 + rbase + rr)*DCOL;
      #pragma unroll
      for (int i=0;i<8;++i){ const int e = lane + i*64; xv[rr][i] = (e < DCOL) ? xr[e] : 0.f; }
    }
    float wA[8], wB[8]; int uu[8], mmv[8];
    #pragma unroll
    for (int i=0;i<8;++i){
      const int e = lane + i*64;
      if (e < 128){ uu[i]=e; mmv[i]=0; wA[i]=nw0[e]; wB[i]=nb0[e]; }
      else if (e < 320){ const int d=e-128; const int u=d/3; uu[i]=u; mmv[i]=d-3*u; wA[i]=nw1[u]; wB[i]=0.f; }
      else if (e < DCOL){ const int d=e-320; const int u=d/5; uu[i]=u; mmv[i]=d-5*u; wA[i]=nw2[u]; wB[i]=0.f; }
      else { uu[i]=0; mmv[i]=0; wA[i]=0.f; wB[i]=0.f; }
    }
    #pragma unroll
    for (int rr=0; rr<2; ++rr){
      const int r = rbase + rr;
      float s0  = xv[rr][0] + xv[rr][1];
      float s0q = xv[rr][0]*xv[rr][0] + xv[rr][1]*xv[rr][1];
      float q1  = xv[rr][2]*xv[rr][2] + xv[rr][3]*xv[rr][3] + xv[rr][4]*xv[rr][4];
      float q2  = xv[rr][5]*xv[rr][5] + xv[rr][6]*xv[rr][6] + xv[rr][7]*xv[rr][7];
      #pragma unroll
      for (int off=32; off>0; off>>=1){
        s0  += __shfl_xor(s0,  off);
        s0q += __shfl_xor(s0q, off);
        q1  += __shfl_xor(q1,  off);
        q2  += __shfl_xor(q2,  off);
      }
      const float mu   = s0 * (1.f/128.f);
      const float var  = s0q * (1.f/128.f) - mu*mu;
      const float rstd = rsqrtf(var + 1e-8f);
      const float inv  = rsqrtf(0.5f*(q1*(1.f/192.f) + q2*(1.f/160.f)) + 1e-8f);
      #pragma unroll
      for (int i=0;i<8;++i){
        const int e = lane + i*64;
        if (e < 128)       y0bf[r][e] = f2bf((xv[rr][i]-mu)*rstd*wA[i] + wB[i]);
        else if (e < 320)  y1bf[mmv[i]][r][uu[i]] = f2bf(xv[rr][i]*inv*wA[i]);
        else if (e < DCOL) y2bf[mmv[i]][r][uu[i]] = f2bf(xv[rr][i]*inv*wA[i]);
      }
    }
  }
  __syncthreads();

  // ---------- P2: h0 = y0@W0 + b0 -> silu/sigmoid -> sbf/gbf (7 tiles/wave, ping-pong) ----------
  {
    short8 a0[4];
    #pragma unroll
    for (int kk=0; kk<4; ++kk)
      a0[kk] = *(const short8*)&y0bf[lane16][kk*32 + quad*8];
    const uint16_t* W0t = wt + OFF_W0T;

    auto ldW0 = [&](int tile, short8* dst){
      #pragma unroll
      for (int kk=0;kk<4;++kk)
        dst[kk] = *(const short8*)(W0t + (size_t)(tile*16+lane16)*128 + kk*32 + quad*8);
    };
    auto h0_tile = [&](int tile, const short8* bfr){
      floatx4 acc = fz;
      #pragma unroll
      for (int kk=0;kk<4;++kk) acc = MFMA16(a0[kk], bfr[kk], acc);
      const int col  = tile*16 + lane16;
      const float bias = b0[col];
      #pragma unroll
      for (int r2=0; r2<4; ++r2){
        const int row = quad*4 + r2;
        const float h  = acc[r2] + bias;
        const float sg = 1.f/(1.f + __expf(-h));
        if (col < 512) sbf[row][col]       = f2bf(h*sg);   // silu
        else           gbf[row][col - 512] = f2bf(sg);     // gate
      }
    };

    short8 buf[2][4];
    ldW0(wave, buf[0]);
    #pragma unroll
    for (int it=0; it<7; ++it){          // tiles wave, wave+8, ..., wave+48
      const int cur = it & 1;
      if (it < 6) ldW0(wave + (it+1)*8, buf[cur^1]);
      h0_tile(wave + it*8, buf[cur]);
    }
  }
  __syncthreads();

  // ---------- W1: o0 = s@V0 + c0 (tile=wave) ∥ h2 ALL m -> z2x5 (w-tile=wave) ----------
  {
    const uint16_t* W2t = wt + OFF_W2T;
    const uint16_t* V0t = wt + OFF_V0T;
    const int col = wave*16 + lane16;           // [0,128): o0 col AND h2 w-col
    // early loads: h2 B (shared across 5 m) + a2[m] + gates + o0 residual x
    const short8 b2 = *(const short8*)(W2t + (size_t)col*32 + quad*8);
    short8 a2[5];
    #pragma unroll
    for (int m=0;m<5;++m) a2[m] = *(const short8*)&y2bf[m][lane16][quad*8];
    float g2v[4], xra[4];
    #pragma unroll
    for (int r2=0;r2<4;++r2){
      g2v[r2] = bf2f(gbf[quad*4+r2][256+col]);
      xra[r2] = x[(size_t)(row0+quad*4+r2)*DCOL + col];
    }
    const float cc = c0[col];
    floatx4 acc = fz;
    #pragma unroll 4
    for (int kk=0; kk<16; ++kk){
      const short8 a = *(const short8*)&sbf[lane16][kk*32 + quad*8];
      const short8 b = *(const short8*)(V0t + (size_t)col*512 + kk*32 + quad*8);
      acc = MFMA16(a, b, acc);
    }
    #pragma unroll
    for (int m=0;m<5;++m){
      floatx4 h = MFMA16(a2[m], b2, fz);
      #pragma unroll
      for (int r2=0;r2<4;++r2)
        z2bf[m][quad*4+r2][col] = f2bf(h[r2]*g2v[r2]);
    }
    #pragma unroll
    for (int r2=0;r2<4;++r2)
      out[(size_t)(row0+quad*4+r2)*DCOL + col] = xra[r2] + ta*(acc[r2]+cc);
  }
  __syncthreads();

  // ---------- W2: h1 ALL m -> z1x3 (waves 0-5) ∥ o2 ALL m (waves 6,7, reads z2) ----------
  {
    if (wave < 6){
      const uint16_t* W1t = wt + OFF_W1T;
      short8 a1[3][2];
      #pragma unroll
      for (int m=0;m<3;++m){
        a1[m][0] = *(const short8*)&y1bf[m][lane16][quad*8];
        a1[m][1] = *(const short8*)&y1bf[m][lane16][32 + quad*8];
      }
      const int nt    = (wave < 4) ? 3 : 2;
      const int tbase = (wave < 4) ? wave*3 : 12 + (wave-4)*2;
      #pragma unroll 1
      for (int tt=0; tt<nt; ++tt){
        const int col = (tbase+tt)*16 + lane16;      // [0,256)
        const short8 b0f = *(const short8*)(W1t + (size_t)col*64 + quad*8);
        const short8 b1f = *(const short8*)(W1t + (size_t)col*64 + 32 + quad*8);
        float gv[4];
        #pragma unroll
        for (int r2=0;r2<4;++r2) gv[r2] = bf2f(gbf[quad*4+r2][col]);
        #pragma unroll
        for (int m=0;m<3;++m){
          floatx4 am = MFMA16(a1[m][0], b0f, fz);
          am = MFMA16(a1[m][1], b1f, am);
          #pragma unroll
          for (int r2=0;r2<4;++r2)
            z1bf[m][quad*4+r2][col] = f2bf(am[r2]*gv[r2]);
        }
      }
    } else {
      const uint16_t* V2t = wt + OFF_V2T;
      const int col = (wave-6)*16 + lane16;          // [0,32)
      short8 ob[4];
      #pragma unroll
      for (int kk=0;kk<4;++kk)
        ob[kk] = *(const short8*)(V2t + (size_t)col*128 + kk*32 + quad*8);
      float xo[5][4];
      #pragma unroll
      for (int m=0;m<5;++m)
        #pragma unroll
        for (int r2=0;r2<4;++r2)
          xo[m][r2] = x[(size_t)(row0+quad*4+r2)*DCOL + 320 + col*5 + m];
      floatx4 am[5];
      #pragma unroll
      for (int m=0;m<5;++m){
        am[m] = fz;
        #pragma unroll
        for (int kk=0;kk<4;++kk){
          const short8 a = *(const short8*)&z2bf[m][lane16][kk*32 + quad*8];
          am[m] = MFMA16(a, ob[kk], am[m]);
        }
      }
      #pragma unroll
      for (int m=0;m<5;++m)
        #pragma unroll
        for (int r2=0;r2<4;++r2){
          const size_t idx = (size_t)(row0+quad*4+r2)*DCOL + 320 + col*5 + m;
          out[idx] = xo[m][r2] + ta*am[m][r2];
        }
    }
  }
  __syncthreads();

  // ---------- W3: o1 ALL m (reads z1; waves 0-3: m=0,2; waves 4-7: m=1; same cols) ----------
  {
    const uint16_t* V1t = wt + OFF_V1T;
    const int col = (wave & 3)*16 + lane16;          // [0,64)
    short8 vb[8];
    #pragma unroll
    for (int kk=0;kk<8;++kk)
      vb[kk] = *(const short8*)(V1t + (size_t)col*256 + kk*32 + quad*8);
    if (wave < 4){
      float xr0[4], xr2[4];
      #pragma unroll
      for (int r2=0;r2<4;++r2){
        const size_t base = (size_t)(row0+quad*4+r2)*DCOL + 128 + col*3;
        xr0[r2] = x[base + 0];
        xr2[r2] = x[base + 2];
      }
      floatx4 am0 = fz, am2 = fz;
      #pragma unroll
      for (int kk=0;kk<8;++kk){
        const short8 f0 = *(const short8*)&z1bf[0][lane16][kk*32 + quad*8];
        const short8 f2 = *(const short8*)&z1bf[2][lane16][kk*32 + quad*8];
        am0 = MFMA16(f0, vb[kk], am0);
        am2 = MFMA16(f2, vb[kk], am2);
      }
      #pragma unroll
      for (int r2=0;r2<4;++r2){
        const size_t base = (size_t)(row0+quad*4+r2)*DCOL + 128 + col*3;
        out[base + 0] = xr0[r2] + ta*am0[r2];
        out[base + 2] = xr2[r2] + ta*am2[r2];
      }
    } else {
      float xr1[4];
      #pragma unroll
      for (int r2=0;r2<4;++r2)
        xr1[r2] = x[(size_t)(row0+quad*4+r2)*DCOL + 128 + col*3 + 1];
      floatx4 am1 = fz;
      #pragma unroll
      for (int kk=0;kk<8;++kk){
        const short8 f1 = *(const short8*)&z1bf[1][lane16][kk*32 + quad*8];
        am1 = MFMA16(f1, vb[kk], am1);
      }
      #pragma unroll
      for (int r2=0;r2<4;++r2)
        out[(size_t)(row0+quad*4+r2)*DCOL + 128 + col*3 + 1] = xr1[r2] + ta*am1[r2];
    }
  }
}

extern "C" void kernel_launch(void* const* d_in, const int* in_sizes, int n_in,
                              void* d_out, int out_size, void* d_ws, size_t ws_size,
                              hipStream_t stream) {
  const float* x   = (const float*)d_in[0];
  const float* nw0 = (const float*)d_in[1];
  const float* nb0 = (const float*)d_in[2];
  const float* nw1 = (const float*)d_in[3];
  const float* nw2 = (const float*)d_in[4];
  const float* W0  = (const float*)d_in[5];
  const float* b0  = (const float*)d_in[6];
  const float* W1  = (const float*)d_in[7];
  const float* W2  = (const float*)d_in[8];
  const float* V0  = (const float*)d_in[9];
  const float* c0  = (const float*)d_in[10];
  const float* V1  = (const float*)d_in[11];
  const float* V2  = (const float*)d_in[12];
  const float* al  = (const float*)d_in[13];
  uint16_t* wt = (uint16_t*)d_ws;   // needs 442368 B

  convert_weights<<<dim3((TOT_W + 255)/256), dim3(256), 0, stream>>>(
      W0, W1, W2, V0, V1, V2, wt);
  ffn_mfma<<<dim3(NROWS/RT), dim3(512), 0, stream>>>(
      x, nw0, nb0, nw1, nw2, b0, c0, al, wt, (float*)d_out);
}

// Round 5
// 429.635 us; speedup vs baseline: 1.2350x; 1.0006x over previous
//
#include <hip/hip_runtime.h>
#include <stdint.h>

#define NROWS 65536
#define DCOL  480      // 128 + 3*64 + 5*32
#define RT    16       // rows per block

#define INV_S0 0.08838834764831845f   // 1/sqrt(128)
#define INV_S1 0.125f                  // 1/8
#define INV_S2 0.17677669529663687f    // 1/sqrt(32)
#define INV_T0 0.044194173824159216f   // 1/sqrt(512)
#define INV_T1 0.0625f                 // 1/16
#define INV_T2 0.08838834764831845f    // 1/sqrt(128)

// d_ws element offsets (uint16_t units), fragment-linear transposed layouts Wt[n][k]
#define OFF_W0T 0         // [896][128]  (x INV_S0 folded)
#define OFF_W1T 114688    // [256][64]   (x INV_S1)
#define OFF_W2T 131072    // [128][32]   (x INV_S2)
#define OFF_V0T 135168    // [128][512]  (x INV_T0)
#define OFF_V1T 200704    // [64][256]   (x INV_T1)
#define OFF_V2T 217088    // [32][128]   (x INV_T2)
#define TOT_W   221184

typedef __attribute__((ext_vector_type(8))) short  short8;
typedef __attribute__((ext_vector_type(4))) float  floatx4;

__device__ __forceinline__ uint16_t f2bf(float x){
  uint32_t u = __builtin_bit_cast(uint32_t, x);
  return (uint16_t)((u + 0x8000u) >> 16);
}
__device__ __forceinline__ float bf2f(uint16_t h){
  return __builtin_bit_cast(float, (uint32_t)h << 16);
}

#define MFMA16(a,b,c) __builtin_amdgcn_mfma_f32_16x16x32_bf16((a),(b),(c),0,0,0)

// ---------------- weight conversion pre-pass: fp32 row-major -> bf16 Wt[n][k], scale folded
__global__ __launch_bounds__(256)
void convert_weights(const float* __restrict__ W0, const float* __restrict__ W1,
                     const float* __restrict__ W2, const float* __restrict__ V0,
                     const float* __restrict__ V1, const float* __restrict__ V2,
                     uint16_t* __restrict__ wt)
{
  const int tid = blockIdx.x*256 + threadIdx.x;
  if (tid >= TOT_W) return;
  if (tid < OFF_W1T){
    const int i = tid;            const int n = i>>7, k = i&127;
    wt[tid] = f2bf(W0[(size_t)k*896 + n] * INV_S0);
  } else if (tid < OFF_W2T){
    const int i = tid - OFF_W1T;  const int n = i>>6, k = i&63;
    wt[tid] = f2bf(W1[(size_t)k*256 + n] * INV_S1);
  } else if (tid < OFF_V0T){
    const int i = tid - OFF_W2T;  const int n = i>>5, k = i&31;
    wt[tid] = f2bf(W2[(size_t)k*128 + n] * INV_S2);
  } else if (tid < OFF_V1T){
    const int i = tid - OFF_V0T;  const int n = i>>9, k = i&511;
    wt[tid] = f2bf(V0[(size_t)k*128 + n] * INV_T0);
  } else if (tid < OFF_V2T){
    const int i = tid - OFF_V1T;  const int n = i>>8, k = i&255;
    wt[tid] = f2bf(V1[(size_t)k*64 + n] * INV_T1);
  } else {
    const int i = tid - OFF_V2T;  const int n = i>>7, k = i&127;
    wt[tid] = f2bf(V2[(size_t)k*32 + n] * INV_T2);
  }
}

// ---------------- fused main kernel: 16 rows / 8 waves / 4 barriers, line-dense writes
// Schedule: P1(norms) | P2(h0 -> s,g) | W1(o0 ∥ h2 all-m -> z2x5) |
//           W2(h1 all-m -> z1x3 ∥ o2 all-m reads z2) | W3(o1 all-m reads z1)
// R5 change vs R4: deep named-register prefetch everywhere (W1: all 16 V0 frags
// upfront + dual accumulators; P2: 2-tiles-ahead 3-buffer rotation; W2: all B
// frags upfront) — attacks exposed load latency (R4: VGPR=52, waves stall 15x
// their issue time). LDS layout/occupancy identical to R4.
// LDS pool 68608 B (lifetime-overlapped), 2 blocks/CU x 8 waves = 16 waves/CU.
__global__ __launch_bounds__(512, 4)
void ffn_mfma(const float* __restrict__ x,  const float* __restrict__ nw0,
              const float* __restrict__ nb0,const float* __restrict__ nw1,
              const float* __restrict__ nw2,const float* __restrict__ b0,
              const float* __restrict__ c0, const float* __restrict__ alpha,
              const uint16_t* __restrict__ wt, float* __restrict__ out)
{
  __shared__ __align__(16) uint16_t pool[34304];   // 68608 B

  uint16_t (*gbf )[392]      = (uint16_t (*)[392])     (pool);           // [16][392]
  uint16_t (*y1bf)[16][72]   = (uint16_t (*)[16][72])  (pool + 6272);    // [3][16][72]
  uint16_t (*z2bf)[16][136]  = (uint16_t (*)[16][136]) (pool + 9728);    // [5][16][136]
  uint16_t (*z1bf)[16][264]  = (uint16_t (*)[16][264]) (pool + 20608);   // [3][16][264]
  uint16_t (*y2bf)[16][40]   = (uint16_t (*)[16][40])  (pool + 20608);   // [5][16][40]
  uint16_t (*sbf )[520]      = (uint16_t (*)[520])     (pool + 23808);   // [16][520]
  uint16_t (*y0bf)[136]      = (uint16_t (*)[136])     (pool + 32128);   // [16][136]

  const int t      = threadIdx.x;
  const int wave   = t >> 6, lane = t & 63;
  const int lane16 = lane & 15, quad = lane >> 4;
  const int row0   = blockIdx.x * RT;
  const float ta   = tanhf(alpha[0]);
  const floatx4 fz = {0.f,0.f,0.f,0.f};

  // ---------- P1: norms -> y0/y1/y2 (2 rows per wave) ----------
  {
    float xv[2][8];
    const int rbase = wave*2;
    #pragma unroll
    for (int rr=0; rr<2; ++rr){
      const float* xr = x + (size_t)(row0 + rbase + rr)*DCOL;
      #pragma unroll
      for (int i=0;i<8;++i){ const int e = lane + i*64; xv[rr][i] = (e < DCOL) ? xr[e] : 0.f; }
    }
    float wA[8], wB[8]; int uu[8], mmv[8];
    #pragma unroll
    for (int i=0;i<8;++i){
      const int e = lane + i*64;
      if (e < 128){ uu[i]=e; mmv[i]=0; wA[i]=nw0[e]; wB[i]=nb0[e]; }
      else if (e < 320){ const int d=e-128; const int u=d/3; uu[i]=u; mmv[i]=d-3*u; wA[i]=nw1[u]; wB[i]=0.f; }
      else if (e < DCOL){ const int d=e-320; const int u=d/5; uu[i]=u; mmv[i]=d-5*u; wA[i]=nw2[u]; wB[i]=0.f; }
      else { uu[i]=0; mmv[i]=0; wA[i]=0.f; wB[i]=0.f; }
    }
    #pragma unroll
    for (int rr=0; rr<2; ++rr){
      const int r = rbase + rr;
      float s0  = xv[rr][0] + xv[rr][1];
      float s0q = xv[rr][0]*xv[rr][0] + xv[rr][1]*xv[rr][1];
      float q1  = xv[rr][2]*xv[rr][2] + xv[rr][3]*xv[rr][3] + xv[rr][4]*xv[rr][4];
      float q2  = xv[rr][5]*xv[rr][5] + xv[rr][6]*xv[rr][6] + xv[rr][7]*xv[rr][7];
      #pragma unroll
      for (int off=32; off>0; off>>=1){
        s0  += __shfl_xor(s0,  off);
        s0q += __shfl_xor(s0q, off);
        q1  += __shfl_xor(q1,  off);
        q2  += __shfl_xor(q2,  off);
      }
      const float mu   = s0 * (1.f/128.f);
      const float var  = s0q * (1.f/128.f) - mu*mu;
      const float rstd = rsqrtf(var + 1e-8f);
      const float inv  = rsqrtf(0.5f*(q1*(1.f/192.f) + q2*(1.f/160.f)) + 1e-8f);
      #pragma unroll
      for (int i=0;i<8;++i){
        const int e = lane + i*64;
        if (e < 128)       y0bf[r][e] = f2bf((xv[rr][i]-mu)*rstd*wA[i] + wB[i]);
        else if (e < 320)  y1bf[mmv[i]][r][uu[i]] = f2bf(xv[rr][i]*inv*wA[i]);
        else if (e < DCOL) y2bf[mmv[i]][r][uu[i]] = f2bf(xv[rr][i]*inv*wA[i]);
      }
    }
  }
  __syncthreads();

  // ---------- P2: h0 = y0@W0 + b0 -> silu/sigmoid -> sbf/gbf (2-ahead, 3 buffers) ----------
  {
    short8 a0[4];
    #pragma unroll
    for (int kk=0; kk<4; ++kk)
      a0[kk] = *(const short8*)&y0bf[lane16][kk*32 + quad*8];
    const uint16_t* W0t = wt + OFF_W0T;

    auto ldW0 = [&](int tile, short8* dst){
      #pragma unroll
      for (int kk=0;kk<4;++kk)
        dst[kk] = *(const short8*)(W0t + (size_t)(tile*16+lane16)*128 + kk*32 + quad*8);
    };
    auto h0_tile = [&](int tile, const short8* bfr){
      floatx4 acc = fz;
      #pragma unroll
      for (int kk=0;kk<4;++kk) acc = MFMA16(a0[kk], bfr[kk], acc);
      const int col  = tile*16 + lane16;
      const float bias = b0[col];
      #pragma unroll
      for (int r2=0; r2<4; ++r2){
        const int row = quad*4 + r2;
        const float h  = acc[r2] + bias;
        const float sg = 1.f/(1.f + __expf(-h));
        if (col < 512) sbf[row][col]       = f2bf(h*sg);   // silu
        else           gbf[row][col - 512] = f2bf(sg);     // gate
      }
    };

    short8 bufA[4], bufB[4], bufC[4];
    ldW0(wave,      bufA);
    ldW0(wave + 8,  bufB);
    ldW0(wave + 16, bufC);
    h0_tile(wave,      bufA);  ldW0(wave + 24, bufA);
    h0_tile(wave + 8,  bufB);  ldW0(wave + 32, bufB);
    h0_tile(wave + 16, bufC);  ldW0(wave + 40, bufC);
    h0_tile(wave + 24, bufA);  ldW0(wave + 48, bufA);
    h0_tile(wave + 32, bufB);
    h0_tile(wave + 40, bufC);
    h0_tile(wave + 48, bufA);
  }
  __syncthreads();

  // ---------- W1: o0 = s@V0 + c0 (tile=wave, 16 B-frags preloaded, dual acc)
  //             ∥ h2 ALL m -> z2x5 (w-tile=wave) ----------
  {
    const uint16_t* W2t = wt + OFF_W2T;
    const uint16_t* V0t = wt + OFF_V0T;
    const int col = wave*16 + lane16;           // [0,128): o0 col AND h2 w-col
    // issue the lone W2 B load first (needed at the tail)
    const short8 b2 = *(const short8*)(W2t + (size_t)col*32 + quad*8);
    // all 16 V0 fragments in flight at once: one L2 round-trip for the whole loop
    short8 vb[16];
    #pragma unroll
    for (int kk=0;kk<16;++kk)
      vb[kk] = *(const short8*)(V0t + (size_t)col*512 + kk*32 + quad*8);
    float xra[4];
    #pragma unroll
    for (int r2=0;r2<4;++r2)
      xra[r2] = x[(size_t)(row0+quad*4+r2)*DCOL + col];
    const float cc = c0[col];

    floatx4 accA = fz, accB = fz;               // split dependent MFMA chain
    #pragma unroll
    for (int kk=0; kk<8; ++kk){
      const short8 a = *(const short8*)&sbf[lane16][kk*32 + quad*8];
      accA = MFMA16(a, vb[kk], accA);
    }
    #pragma unroll
    for (int kk=8; kk<16; ++kk){
      const short8 a = *(const short8*)&sbf[lane16][kk*32 + quad*8];
      accB = MFMA16(a, vb[kk], accB);
    }
    // h2 (LDS-side operands late: LDS latency is short)
    short8 a2[5];
    #pragma unroll
    for (int m=0;m<5;++m) a2[m] = *(const short8*)&y2bf[m][lane16][quad*8];
    float g2v[4];
    #pragma unroll
    for (int r2=0;r2<4;++r2) g2v[r2] = bf2f(gbf[quad*4+r2][256+col]);
    #pragma unroll
    for (int m=0;m<5;++m){
      floatx4 h = MFMA16(a2[m], b2, fz);
      #pragma unroll
      for (int r2=0;r2<4;++r2)
        z2bf[m][quad*4+r2][col] = f2bf(h[r2]*g2v[r2]);
    }
    #pragma unroll
    for (int r2=0;r2<4;++r2)
      out[(size_t)(row0+quad*4+r2)*DCOL + col] = xra[r2] + ta*(accA[r2]+accB[r2]+cc);
  }
  __syncthreads();

  // ---------- W2: h1 ALL m -> z1x3 (waves 0-5, B-frags preloaded) ∥ o2 ALL m (waves 6,7) ----------
  {
    if (wave < 4){
      const uint16_t* W1t = wt + OFF_W1T;
      // 3 tiles: cols (wave*3+tt)*16 + lane16 ; all 6 B-frags in flight upfront
      short8 wb[3][2];
      #pragma unroll
      for (int tt=0;tt<3;++tt){
        const int col = (wave*3+tt)*16 + lane16;
        wb[tt][0] = *(const short8*)(W1t + (size_t)col*64 + quad*8);
        wb[tt][1] = *(const short8*)(W1t + (size_t)col*64 + 32 + quad*8);
      }
      short8 a1[3][2];
      #pragma unroll
      for (int m=0;m<3;++m){
        a1[m][0] = *(const short8*)&y1bf[m][lane16][quad*8];
        a1[m][1] = *(const short8*)&y1bf[m][lane16][32 + quad*8];
      }
      #pragma unroll
      for (int tt=0;tt<3;++tt){
        const int col = (wave*3+tt)*16 + lane16;
        float gv[4];
        #pragma unroll
        for (int r2=0;r2<4;++r2) gv[r2] = bf2f(gbf[quad*4+r2][col]);
        #pragma unroll
        for (int m=0;m<3;++m){
          floatx4 am = MFMA16(a1[m][0], wb[tt][0], fz);
          am = MFMA16(a1[m][1], wb[tt][1], am);
          #pragma unroll
          for (int r2=0;r2<4;++r2)
            z1bf[m][quad*4+r2][col] = f2bf(am[r2]*gv[r2]);
        }
      }
    } else if (wave < 6){
      const uint16_t* W1t = wt + OFF_W1T;
      // 2 tiles: cols (12+(wave-4)*2+tt)*16 + lane16
      short8 wb[2][2];
      #pragma unroll
      for (int tt=0;tt<2;++tt){
        const int col = (12+(wave-4)*2+tt)*16 + lane16;
        wb[tt][0] = *(const short8*)(W1t + (size_t)col*64 + quad*8);
        wb[tt][1] = *(const short8*)(W1t + (size_t)col*64 + 32 + quad*8);
      }
      short8 a1[3][2];
      #pragma unroll
      for (int m=0;m<3;++m){
        a1[m][0] = *(const short8*)&y1bf[m][lane16][quad*8];
        a1[m][1] = *(const short8*)&y1bf[m][lane16][32 + quad*8];
      }
      #pragma unroll
      for (int tt=0;tt<2;++tt){
        const int col = (12+(wave-4)*2+tt)*16 + lane16;
        float gv[4];
        #pragma unroll
        for (int r2=0;r2<4;++r2) gv[r2] = bf2f(gbf[quad*4+r2][col]);
        #pragma unroll
        for (int m=0;m<3;++m){
          floatx4 am = MFMA16(a1[m][0], wb[tt][0], fz);
          am = MFMA16(a1[m][1], wb[tt][1], am);
          #pragma unroll
          for (int r2=0;r2<4;++r2)
            z1bf[m][quad*4+r2][col] = f2bf(am[r2]*gv[r2]);
        }
      }
    } else {
      const uint16_t* V2t = wt + OFF_V2T;
      const int col = (wave-6)*16 + lane16;          // [0,32)
      short8 ob[4];
      #pragma unroll
      for (int kk=0;kk<4;++kk)
        ob[kk] = *(const short8*)(V2t + (size_t)col*128 + kk*32 + quad*8);
      float xo[5][4];
      #pragma unroll
      for (int m=0;m<5;++m)
        #pragma unroll
        for (int r2=0;r2<4;++r2)
          xo[m][r2] = x[(size_t)(row0+quad*4+r2)*DCOL + 320 + col*5 + m];
      floatx4 am[5];
      #pragma unroll
      for (int m=0;m<5;++m){
        am[m] = fz;
        #pragma unroll
        for (int kk=0;kk<4;++kk){
          const short8 a = *(const short8*)&z2bf[m][lane16][kk*32 + quad*8];
          am[m] = MFMA16(a, ob[kk], am[m]);
        }
      }
      #pragma unroll
      for (int m=0;m<5;++m)
        #pragma unroll
        for (int r2=0;r2<4;++r2){
          const size_t idx = (size_t)(row0+quad*4+r2)*DCOL + 320 + col*5 + m;
          out[idx] = xo[m][r2] + ta*am[m][r2];
        }
    }
  }
  __syncthreads();

  // ---------- W3: o1 ALL m (reads z1; waves 0-3: m=0,2; waves 4-7: m=1; same cols) ----------
  {
    const uint16_t* V1t = wt + OFF_V1T;
    const int col = (wave & 3)*16 + lane16;          // [0,64)
    short8 vb[8];
    #pragma unroll
    for (int kk=0;kk<8;++kk)
      vb[kk] = *(const short8*)(V1t + (size_t)col*256 + kk*32 + quad*8);
    if (wave < 4){
      float xr0[4], xr2[4];
      #pragma unroll
      for (int r2=0;r2<4;++r2){
        const size_t base = (size_t)(row0+quad*4+r2)*DCOL + 128 + col*3;
        xr0[r2] = x[base + 0];
        xr2[r2] = x[base + 2];
      }
      floatx4 am0 = fz, am2 = fz;
      #pragma unroll
      for (int kk=0;kk<8;++kk){
        const short8 f0 = *(const short8*)&z1bf[0][lane16][kk*32 + quad*8];
        const short8 f2 = *(const short8*)&z1bf[2][lane16][kk*32 + quad*8];
        am0 = MFMA16(f0, vb[kk], am0);
        am2 = MFMA16(f2, vb[kk], am2);
      }
      #pragma unroll
      for (int r2=0;r2<4;++r2){
        const size_t base = (size_t)(row0+quad*4+r2)*DCOL + 128 + col*3;
        out[base + 0] = xr0[r2] + ta*am0[r2];
        out[base + 2] = xr2[r2] + ta*am2[r2];
      }
    } else {
      float xr1[4];
      #pragma unroll
      for (int r2=0;r2<4;++r2)
        xr1[r2] = x[(size_t)(row0+quad*4+r2)*DCOL + 128 + col*3 + 1];
      floatx4 am1 = fz;
      #pragma unroll
      for (int kk=0;kk<8;++kk){
        const short8 f1 = *(const short8*)&z1bf[1][lane16][kk*32 + quad*8];
        am1 = MFMA16(f1, vb[kk], am1);
      }
      #pragma unroll
      for (int r2=0;r2<4;++r2)
        out[(size_t)(row0+quad*4+r2)*DCOL + 128 + col*3 + 1] = xr1[r2] + ta*am1[r2];
    }
  }
}

extern "C" void kernel_launch(void* const* d_in, const int* in_sizes, int n_in,
                              void* d_out, int out_size, void* d_ws, size_t ws_size,
                              hipStream_t stream) {
  const float* x   = (const float*)d_in[0];
  const float* nw0 = (const float*)d_in[1];
  const float* nb0 = (const float*)d_in[2];
  const float* nw1 = (const float*)d_in[3];
  const float* nw2 = (const float*)d_in[4];
  const float* W0  = (const float*)d_in[5];
  const float* b0  = (const float*)d_in[6];
  const float* W1  = (const float*)d_in[7];
  const float* W2  = (const float*)d_in[8];
  const float* V0  = (const float*)d_in[9];
  const float* c0  = (const float*)d_in[10];
  const float* V1  = (const float*)d_in[11];
  const float* V2  = (const float*)d_in[12];
  const float* al  = (const float*)d_in[13];
  uint16_t* wt = (uint16_t*)d_ws;   // needs 442368 B

  convert_weights<<<dim3((TOT_W + 255)/256), dim3(256), 0, stream>>>(
      W0, W1, W2, V0, V1, V2, wt);
  ffn_mfma<<<dim3(NROWS/RT), dim3(512), 0, stream>>>(
      x, nw0, nb0, nw1, nw2, b0, c0, al, wt, (float*)d_out);
}